// Round 7
// baseline (295.383 us; speedup 1.0000x reference)
//
#include <hip/hip_runtime.h>
#include <math.h>

#define HID 256
#define EPS_REG 1e-6

typedef __attribute__((ext_vector_type(8)))  short short8;
typedef __attribute__((ext_vector_type(4)))  short short4v;
typedef __attribute__((ext_vector_type(16))) float v16f;

#define MFMA32(a, b, c) __builtin_amdgcn_mfma_f32_32x32x16_bf16((a), (b), (c), 0, 0, 0)

// ---------------------------------------------------------------------------
// Fast tanh: tanh(z) = 1 - 2/(exp(2z)+1). ~6 instr, <=2 ulp.
// ---------------------------------------------------------------------------
__device__ __forceinline__ float fast_tanh(float z) {
    const float e = __expf(2.0f * z);
    const float d = e + 1.0f;
    float r = __builtin_amdgcn_rcpf(d);
    r = r * (2.0f - d * r);              // Newton refine to full fp32
    return fmaf(-2.0f, r, 1.0f);
}

// ---------------------------------------------------------------------------
// RTN bf16 3-way split: v ~= hi + mid + lo. R18 lesson: 2-way (err ~2^-17)
// FAILS the 1402 absmax budget (11520). 6-product bf16x3 is the floor.
// ---------------------------------------------------------------------------
__device__ __forceinline__ float rtn_bf16(float v, short* s) {
    unsigned r = (__float_as_uint(v) + 0x8000u) & 0xFFFF0000u;
    *s = (short)(r >> 16);
    return __uint_as_float(r);
}
__device__ __forceinline__ void split3(float v, short* a, short* b, short* c) {
    float f0 = rtn_bf16(v, a);
    float r1 = v - f0;
    float f1 = rtn_bf16(r1, b);
    float r2 = r1 - f1;
    (void)rtn_bf16(r2, c);
}

// ---------------------------------------------------------------------------
// R20: 32x32x16 MFMA shape (2495 vs 2075 TF ubench -> MFMA term 99->83us).
// A-frag layout (extrapolated from verified 16x16 pattern):
//   lane holds A[row = rt*32 + (lane&31)][k = ks*16 + (lane>>5)*8 + e]
// B-frag symmetric: B[k = ks*16 + (lane>>5)*8 + e][col = lane&31]
// C/D (HW-measured, guide m74/m101): col=lane&31, row=(reg&3)+8(reg>>2)+4(lane>>5)
// prep: A1 = W1 rows (phase 1), A2 = W1^T (phase 2). 6 x 128KB = 768KB.
// ---------------------------------------------------------------------------
__global__ void prep_w1_frags(const float* __restrict__ W1, short* __restrict__ ws) {
    const int gid   = blockIdx.x * 128 + threadIdx.x;   // 0..16383
    const int lane  = gid & 63;
    const int kstep = (gid >> 6) & 15;
    const int rt    = (gid >> 10) & 7;
    const int which = gid >> 13;                        // 0: A1, 1: A2
    const int r32   = lane & 31;
    const int kh    = lane >> 5;

    float v[8];
    if (which == 0) {
        const float* p = W1 + (size_t)(rt*32 + r32)*HID + kstep*16 + kh*8;
        const float4 va = *(const float4*)(p);
        const float4 vb = *(const float4*)(p + 4);
        v[0]=va.x; v[1]=va.y; v[2]=va.z; v[3]=va.w;
        v[4]=vb.x; v[5]=vb.y; v[6]=vb.z; v[7]=vb.w;
    } else {
        const float* p = W1 + (size_t)(kstep*16 + kh*8)*HID + rt*32 + r32;
#pragma unroll
        for (int t = 0; t < 8; ++t) v[t] = p[(size_t)t*HID];
    }
    short8 h8, m8, l8;
#pragma unroll
    for (int t = 0; t < 8; ++t) {
        short sh, sm, sl;
        split3(v[t], &sh, &sm, &sl);
        h8[t] = sh; m8[t] = sm; l8[t] = sl;
    }
    const size_t base = (size_t)which*196608 + ((size_t)(rt*16 + kstep)*64 + lane)*8;
    *(short8*)(ws + base)          = h8;
    *(short8*)(ws + base + 65536)  = m8;
    *(short8*)(ws + base + 131072) = l8;
}

// LDS B-frag layout: addr = buf*8192 + (ks*64 + lane)*8 + e  (shorts)
// buf 0=hi 1=mid 2=lo; 16 ksteps. Total 24576 shorts = 49152 B.
// U0 overlay (9216 fl) + P3 scratch (8*425 fl) top out at 25232 shorts.
#define SMEM_SHORTS 25248

// ---- Phase 0: layer-0 forward + tangents --> M0 + B1 frags ----------------
// thread: col = tid&31 (s = col>>2, comp = col&3), j-range = (tid>>5)*16.
// Quad-dedup: each quad lane computes h for 4 of the 16 j's; h shared by shfl.
// Stores are dense sequential ds_write_b128 (ideal bank pattern).
__device__ __forceinline__ void lnn_phase0(const float* __restrict__ x,
    const float* __restrict__ W0, const float* __restrict__ b0,
    int samp_base, short* __restrict__ Bf, float* __restrict__ M0, int tid)
{
    const int col  = tid & 31;
    const int s    = col >> 2;
    const int comp = col & 3;
    const int grp  = tid >> 5;           // 0..15
    const int jb   = grp * 16;
    const int lane = tid & 63;

    const float* xs = x + (size_t)(samp_base + s)*7;
    float xv[7];
#pragma unroll
    for (int d = 0; d < 7; ++d) xv[d] = xs[d];

    // own 4 j's: j = jb + comp*4 + jj
    float hown[4];
#pragma unroll
    for (int jj = 0; jj < 4; ++jj) {
        const int j = jb + comp*4 + jj;
        float z = b0[j];
#pragma unroll
        for (int d = 0; d < 7; ++d) z = fmaf(W0[j*7 + d], xv[d], z);
        hown[jj] = fast_tanh(z);
        M0[j*9 + s] = hown[jj];
    }

#pragma unroll
    for (int oct = 0; oct < 2; ++oct) {
        short8 vh, vm, vl;
#pragma unroll
        for (int k = 0; k < 8; ++k) {
            const int jidx = oct*8 + k;
            const int j = jb + jidx;
            const int owner = (lane & ~3) | (jidx >> 2);
            float hsrc;
            switch (jidx & 3) {          // compile-time after unroll
                case 0: hsrc = hown[0]; break;
                case 1: hsrc = hown[1]; break;
                case 2: hsrc = hown[2]; break;
                default: hsrc = hown[3]; break;
            }
            const float h  = __shfl(hsrc, owner, 64);
            const float sg = 1.0f - h*h;
            const float val = (comp == 0) ? h : (sg * W0[j*7 + 3 + comp]);
            short sh, sm, sl;
            split3(val, &sh, &sm, &sl);
            vh[k] = sh; vm[k] = sm; vl[k] = sl;
        }
        const int o = grp*2 + oct;       // j-octet index = kstep*2 + khalf
        const int a = (o*32 + col)*8;
        *(short8*)(&Bf[a])         = vh;
        *(short8*)(&Bf[a + 8192])  = vm;
        *(short8*)(&Bf[a + 16384]) = vl;
    }
}

// ---- MFMA k-loop: acc += A x B (bf16x3, 6-product), 32x32x16 --------------
__device__ __forceinline__ void lnn_mm32(const short8* __restrict__ Ah,
    const short8* __restrict__ Am, const short8* __restrict__ Al,
    const short* __restrict__ Bf, int w, int lane, v16f& acc)
{
    short8 pah[2], pam[2], pal[2];       // A dbuf prefetch
    {
        const size_t fi = ((size_t)(w*16))*64 + lane;
        pah[0] = Ah[fi]; pam[0] = Am[fi]; pal[0] = Al[fi];
    }
#pragma unroll
    for (int ks = 0; ks < 16; ++ks) {
        const int cur = ks & 1, nxt = cur ^ 1;
        if (ks < 15) {
            const size_t fi = ((size_t)(w*16 + ks + 1))*64 + lane;
            pah[nxt] = Ah[fi]; pam[nxt] = Am[fi]; pal[nxt] = Al[fi];
        }
        const int a = (ks*64 + lane)*8;
        const short8 bh = *(const short8*)(&Bf[a]);
        const short8 bm = *(const short8*)(&Bf[a + 8192]);
        const short8 bl = *(const short8*)(&Bf[a + 16384]);
        const short8 ah = pah[cur], am = pam[cur], al = pal[cur];
        acc = MFMA32(ah, bl, acc);
        acc = MFMA32(al, bh, acc);
        acc = MFMA32(am, bm, acc);
        acc = MFMA32(am, bh, acc);
        acc = MFMA32(ah, bm, acc);
        acc = MFMA32(ah, bh, acc);
    }
}

// ---- Epilogue 1: layer-2 nonlinearity + reverse seed --> B2 frags ---------
// acc element: col = lane&31 (s,comp), row = (reg&3)+8(reg>>2)+4(lane>>5).
__device__ __forceinline__ void lnn_epi1_32(const v16f& acc, short* __restrict__ Bf,
    const float* __restrict__ b1, const float* __restrict__ W2, int w, int lane)
{
    const int col  = lane & 31;
    const int comp = lane & 3;
    const int hb   = lane >> 5;
    const int ib   = w*32 + 4*hb;
#pragma unroll
    for (int rg = 0; rg < 4; ++rg) {
        short4v ph, pm, pl;
#pragma unroll
        for (int rr = 0; rr < 4; ++rr) {
            const int reg = rg*4 + rr;
            const int i = ib + 8*rg + rr;
            const float z0 = __shfl(acc[reg] + b1[i], lane & ~3, 64);
            const float h1 = fast_tanh(z0);
            const float s1 = 1.0f - h1*h1;
            const float av = acc[reg];
            const float w2i = W2[i];
            const float u  = (comp == 0) ? (w2i*s1)
                                         : (-2.0f*w2i*h1*s1)*av;
            short sh, sm, sl;
            split3(u, &sh, &sm, &sl);
            ph[rr] = sh; pm[rr] = sm; pl[rr] = sl;
        }
        // value at (k=i, col): kstep = w*2 + (rg>>1), lanehi = rg&1, e = 4*hb + rr
        const int a = (((w*2 + (rg>>1))*64) + (((rg & 1) << 5) | col))*8 + 4*hb;
        *(short4v*)(&Bf[a])         = ph;
        *(short4v*)(&Bf[a + 8192])  = pm;
        *(short4v*)(&Bf[a + 16384]) = pl;
    }
}

// ---- Epilogue 2: back through layer-0 --> U0 plain (overlay Bfrag) --------
__device__ __forceinline__ void lnn_epi2_32(const v16f& acc2, short* __restrict__ Bf,
    const float* __restrict__ M0, const float* __restrict__ W0, int w, int lane)
{
    float* U0 = (float*)Bf;              // [j][col], stride 36
    const int col  = lane & 31;
    const int s    = col >> 2;
    const int comp = lane & 3;
    const int hb   = lane >> 5;
#pragma unroll
    for (int rg = 0; rg < 4; ++rg) {
#pragma unroll
        for (int rr = 0; rr < 4; ++rr) {
            const int reg = rg*4 + rr;
            const int j = w*32 + 8*rg + 4*hb + rr;
            const float w0sel = W0[j*7 + 3 + comp];   // dummy read for comp 0
            const float pv = acc2[reg];
            const float p0 = __shfl(pv, lane & ~3, 64);
            const float h0 = M0[j*9 + s];
            const float sg = 1.0f - h0*h0;
            const float t2 = -2.0f * p0 * h0 * sg;
            const float res = (comp == 0) ? (p0*sg)
                                          : fmaf(pv, sg, t2 * w0sel);
            U0[j*36 + col] = res;
        }
    }
}

// ---- Phase 3a: project through W0^T, reduce to per-sample totals ----------
__device__ __forceinline__ void lnn_phase3_sums(const float* __restrict__ W0,
    short* __restrict__ Bf, int w, int tid)
{
    const float* U0 = (const float*)Bf;
    float* scratch = ((float*)Bf) + 9216 + w * 425;   // [25][17]
    const int t = tid & 63;
    float part[25];
#pragma unroll
    for (int qq = 0; qq < 25; ++qq) part[qq] = 0.0f;

#pragma unroll
    for (int m = 0; m < 4; ++m) {
        const int j = t + 64*m;
        const float4 uv = *(const float4*)(&U0[j*36 + w*4]);
        float w0d[7];
#pragma unroll
        for (int d = 0; d < 7; ++d) w0d[d] = W0[j*7 + d];
#pragma unroll
        for (int d = 0; d < 4; ++d) part[d] = fmaf(uv.x, w0d[d], part[d]);
#pragma unroll
        for (int d = 0; d < 7; ++d) {
            part[4  + d] = fmaf(uv.y, w0d[d], part[4  + d]);
            part[11 + d] = fmaf(uv.z, w0d[d], part[11 + d]);
            part[18 + d] = fmaf(uv.w, w0d[d], part[18 + d]);
        }
    }
#pragma unroll
    for (int off = 1; off <= 2; off <<= 1)
#pragma unroll
        for (int qq = 0; qq < 25; ++qq)
            part[qq] += __shfl_xor(part[qq], off, 64);
    {
        const int quad = t >> 2;
        if ((t & 3) == 0) {
#pragma unroll
            for (int e = 0; e < 25; ++e)
                scratch[e*17 + quad] = part[e];
        }
    }
    if (t < 25) {
        float tot = 0.0f;
#pragma unroll
        for (int k = 0; k < 16; ++k) tot += scratch[t*17 + k];
        scratch[t*17 + 16] = tot;
    }
}

// ---- Phase 3b: 8 fp64 solves on lanes 0..7 of wave 0 (dedup'd) ------------
__device__ __forceinline__ void lnn_solve8(const float* __restrict__ x,
    short* __restrict__ Bf, int samp_base, float* __restrict__ out, int tid)
{
    if (tid >= 8) return;
    const int s = tid;
    const float* scratch = ((const float*)Bf) + 9216 + s * 425;
    double g[25];
#pragma unroll
    for (int e = 0; e < 25; ++e) g[e] = (double)scratch[e*17 + 16];

    const float* xs = x + (size_t)(samp_base + s)*7;
    const double x1 = xs[2], x2 = xs[3];
    const double dq0 = xs[4], dq1 = xs[5], dth = xs[6];

    double M[3][3], rhs[3];
#pragma unroll
    for (int i = 0; i < 3; ++i) {
        const double J0 = g[4 + i*7 + 0];
        const double J1 = g[4 + i*7 + 1];
        const double J2 = -x2*g[4 + i*7 + 2] + x1*g[4 + i*7 + 3];
        const double dL = (i == 0) ? g[0]
                        : (i == 1) ? g[1]
                        : (-x2*g[2] + x1*g[3]);
        M[i][0] = g[4 + i*7 + 4] + (i == 0 ? EPS_REG : 0.0);
        M[i][1] = g[4 + i*7 + 5] + (i == 1 ? EPS_REG : 0.0);
        M[i][2] = g[4 + i*7 + 6] + (i == 2 ? EPS_REG : 0.0);
        rhs[i]  = dL - (J0*dq0 + J1*dq1 + J2*dth);
    }
    // branch-free fp64 Cramer / adjugate solve
    const double c00 = M[1][1]*M[2][2] - M[1][2]*M[2][1];
    const double c01 = M[1][2]*M[2][0] - M[1][0]*M[2][2];
    const double c02 = M[1][0]*M[2][1] - M[1][1]*M[2][0];
    const double det = M[0][0]*c00 + M[0][1]*c01 + M[0][2]*c02;
    const double inv = 1.0 / det;
    const double c10 = M[0][2]*M[2][1] - M[0][1]*M[2][2];
    const double c11 = M[0][0]*M[2][2] - M[0][2]*M[2][0];
    const double c12 = M[0][1]*M[2][0] - M[0][0]*M[2][1];
    const double c20 = M[0][1]*M[1][2] - M[0][2]*M[1][1];
    const double c21 = M[0][2]*M[1][0] - M[0][0]*M[1][2];
    const double c22 = M[0][0]*M[1][1] - M[0][1]*M[1][0];
    const double sol0 = (c00*rhs[0] + c10*rhs[1] + c20*rhs[2]) * inv;
    const double sol1 = (c01*rhs[0] + c11*rhs[1] + c21*rhs[2]) * inv;
    const double sol2 = (c02*rhs[0] + c12*rhs[1] + c22*rhs[2]) * inv;

    float* o = out + (size_t)(samp_base + s)*7;
    o[0] = (float)dq0;
    o[1] = (float)dq1;
    o[2] = (float)(-x2*dth);
    o[3] = (float)( x1*dth);
    o[4] = (float)sol0;
    o[5] = (float)sol1;
    o[6] = (float)sol2;
}

// ---------------------------------------------------------------------------
// Main kernel: 8 samples/block, 512 thr, 2 blocks/CU, 32x32x16 MFMA.
// Each wave owns one 32-row tile (rows w*32..w*32+31); N=32 = one tile.
// ---------------------------------------------------------------------------
__global__ __launch_bounds__(512, 4)
void lnn_mfma32(const float* __restrict__ x,
                const float* __restrict__ W0, const float* __restrict__ b0,
                const float* __restrict__ b1, const float* __restrict__ W2,
                const short* __restrict__ ws,
                float* __restrict__ out)
{
    __shared__ __align__(16) short Bfrag[SMEM_SHORTS];
    __shared__ float M0h[HID * 9];

    const int tid   = threadIdx.x;
    const int samp0 = blockIdx.x * 8;
    const int lane  = tid & 63;
    const int w     = tid >> 6;

    lnn_phase0(x, W0, b0, samp0, Bfrag, M0h, tid);
    __syncthreads();

    const short8* A1h = (const short8*)ws;
    const short8* A1m = A1h + 8192;
    const short8* A1l = A1h + 16384;
    const short8* A2h = A1h + 24576;
    const short8* A2m = A1h + 32768;
    const short8* A2l = A1h + 40960;

    v16f acc;
#pragma unroll
    for (int i = 0; i < 16; ++i) acc[i] = 0.0f;
    lnn_mm32(A1h, A1m, A1l, Bfrag, w, lane, acc);
    __syncthreads();

    lnn_epi1_32(acc, Bfrag, b1, W2, w, lane);
    __syncthreads();

    v16f acc2;
#pragma unroll
    for (int i = 0; i < 16; ++i) acc2[i] = 0.0f;
    lnn_mm32(A2h, A2m, A2l, Bfrag, w, lane, acc2);
    __syncthreads();

    lnn_epi2_32(acc2, Bfrag, M0h, W0, w, lane);
    __syncthreads();

    lnn_phase3_sums(W0, Bfrag, w, tid);
    __syncthreads();

    lnn_solve8(x, Bfrag, samp0, out, tid);
}

// ===========================================================================
// Deep fallback (proven round-3 kernel, fp32 VALU): used if ws too small.
// ===========================================================================
#define TS8 8
#define SCP 36

__global__ void transpose_w1(const float* __restrict__ W1, float* __restrict__ W1T) {
    __shared__ float tile[32][33];
    const int bx = blockIdx.x & 7;
    const int by = blockIdx.x >> 3;
    const int tx = threadIdx.x & 31;
    const int ty = threadIdx.x >> 5;
#pragma unroll
    for (int q = 0; q < 4; ++q)
        tile[ty + q*8][tx] = W1[(by*32 + ty + q*8)*HID + bx*32 + tx];
    __syncthreads();
#pragma unroll
    for (int q = 0; q < 4; ++q)
        W1T[(bx*32 + ty + q*8)*HID + by*32 + tx] = tile[tx][ty + q*8];
}

__global__ __launch_bounds__(256, 2)
void lnn_fused(const float* __restrict__ x,
               const float* __restrict__ W0, const float* __restrict__ b0,
               const float* __restrict__ W1, const float* __restrict__ b1,
               const float* __restrict__ W2,
               const float* __restrict__ W1T, const int useT,
               float* __restrict__ out)
{
    __shared__ float M0[HID * SCP];
    __shared__ float U [HID * SCP];
    const int tid   = threadIdx.x;
    const int samp0 = blockIdx.x * TS8;
    {
        const int j = tid;
        float w0r[7];
#pragma unroll
        for (int d = 0; d < 7; ++d) w0r[d] = W0[j*7 + d];
        const float bj = b0[j];
#pragma unroll
        for (int s = 0; s < TS8; ++s) {
            const float* xs = x + (size_t)(samp0 + s)*7;
            float z = bj;
#pragma unroll
            for (int d = 0; d < 7; ++d) z = fmaf(w0r[d], xs[d], z);
            const float h  = tanhf(z);
            const float sg = 1.0f - h*h;
            float4 v = {h, sg * w0r[4], sg * w0r[5], sg * w0r[6]};
            *(float4*)(&M0[j*SCP + s*4]) = v;
        }
    }
    __syncthreads();
    const int it = tid & 63;
    const int ct = tid >> 6;
    float acc[4][8];
#pragma unroll
    for (int r = 0; r < 4; ++r)
#pragma unroll
        for (int c = 0; c < 8; ++c) acc[r][c] = 0.0f;
    if (useT) {
#pragma unroll 4
        for (int j = 0; j < HID; ++j) {
            const float4 w4 = *(const float4*)(W1T + (size_t)j*HID + it*4);
            const float4 ma = *(const float4*)(&M0[j*SCP + ct*8]);
            const float4 mb = *(const float4*)(&M0[j*SCP + ct*8 + 4]);
            const float w[4] = {w4.x, w4.y, w4.z, w4.w};
            const float m[8] = {ma.x, ma.y, ma.z, ma.w, mb.x, mb.y, mb.z, mb.w};
#pragma unroll
            for (int r = 0; r < 4; ++r)
#pragma unroll
                for (int c = 0; c < 8; ++c)
                    acc[r][c] = fmaf(w[r], m[c], acc[r][c]);
        }
    } else {
#pragma unroll 2
        for (int j = 0; j < HID; ++j) {
            float w[4];
#pragma unroll
            for (int r = 0; r < 4; ++r) w[r] = W1[(size_t)(it*4 + r)*HID + j];
            const float4 ma = *(const float4*)(&M0[j*SCP + ct*8]);
            const float4 mb = *(const float4*)(&M0[j*SCP + ct*8 + 4]);
            const float m[8] = {ma.x, ma.y, ma.z, ma.w, mb.x, mb.y, mb.z, mb.w};
#pragma unroll
            for (int r = 0; r < 4; ++r)
#pragma unroll
                for (int c = 0; c < 8; ++c)
                    acc[r][c] = fmaf(w[r], m[c], acc[r][c]);
        }
    }
    {
#pragma unroll
        for (int r = 0; r < 4; ++r) {
            const int i = it*4 + r;
            const float b1i = b1[i];
            const float w2i = W2[i];
#pragma unroll
            for (int cs = 0; cs < 2; ++cs) {
                const float z1 = acc[r][cs*4+0] + b1i;
                const float h1 = tanhf(z1);
                const float s1 = 1.0f - h1*h1;
                float4 uv;
                uv.x = w2i * s1;
                const float m2 = -2.0f * w2i * h1 * s1;
                uv.y = m2 * acc[r][cs*4+1];
                uv.z = m2 * acc[r][cs*4+2];
                uv.w = m2 * acc[r][cs*4+3];
                *(float4*)(&U[i*SCP + ct*8 + cs*4]) = uv;
            }
        }
    }
    __syncthreads();
    float acc2[4][8];
#pragma unroll
    for (int r = 0; r < 4; ++r)
#pragma unroll
        for (int c = 0; c < 8; ++c) acc2[r][c] = 0.0f;
#pragma unroll 4
    for (int i = 0; i < HID; ++i) {
        const float4 w4 = *(const float4*)(W1 + (size_t)i*HID + it*4);
        const float4 ua = *(const float4*)(&U[i*SCP + ct*8]);
        const float4 ub = *(const float4*)(&U[i*SCP + ct*8 + 4]);
        const float w[4] = {w4.x, w4.y, w4.z, w4.w};
        const float m[8] = {ua.x, ua.y, ua.z, ua.w, ub.x, ub.y, ub.z, ub.w};
#pragma unroll
        for (int r = 0; r < 4; ++r)
#pragma unroll
            for (int c = 0; c < 8; ++c)
                acc2[r][c] = fmaf(w[r], m[c], acc2[r][c]);
    }
    __syncthreads();
    {
#pragma unroll
        for (int r = 0; r < 4; ++r) {
            const int j = it*4 + r;
#pragma unroll
            for (int cs = 0; cs < 2; ++cs) {
                const int scb = ct*8 + cs*4;
                const float4 mm = *(const float4*)(&M0[j*SCP + scb]);
                const float h0v = mm.x;
                const float sg  = 1.0f - h0v*h0v;
                const float p   = acc2[r][cs*4+0];
                const float t2  = -2.0f * p * h0v;
                float4 uv;
                uv.x = p * sg;
                uv.y = fmaf(acc2[r][cs*4+1], sg, t2 * mm.y);
                uv.z = fmaf(acc2[r][cs*4+2], sg, t2 * mm.z);
                uv.w = fmaf(acc2[r][cs*4+3], sg, t2 * mm.w);
                *(float4*)(&U[j*SCP + scb]) = uv;
            }
        }
    }
    __syncthreads();
    const int s = tid >> 5;
    const int t = tid & 31;
    float part[25];
#pragma unroll
    for (int qq = 0; qq < 25; ++qq) part[qq] = 0.0f;
#pragma unroll
    for (int m = 0; m < 8; ++m) {
        const int j = t + 32*m;
        const float4 uv = *(const float4*)(&U[j*SCP + s*4]);
        float w0d[7];
#pragma unroll
        for (int d = 0; d < 7; ++d) w0d[d] = W0[j*7 + d];
#pragma unroll
        for (int d = 0; d < 4; ++d) part[d] = fmaf(uv.x, w0d[d], part[d]);
#pragma unroll
        for (int d = 0; d < 7; ++d) {
            part[4  + d] = fmaf(uv.y, w0d[d], part[4  + d]);
            part[11 + d] = fmaf(uv.z, w0d[d], part[11 + d]);
            part[18 + d] = fmaf(uv.w, w0d[d], part[18 + d]);
        }
    }
#pragma unroll
    for (int off = 16; off >= 1; off >>= 1)
#pragma unroll
        for (int qq = 0; qq < 25; ++qq)
            part[qq] += __shfl_xor(part[qq], off, 64);
    if (t == 0) {
        const float* xs = x + (size_t)(samp0 + s)*7;
        const double x1 = xs[2], x2 = xs[3];
        const double dq0 = xs[4], dq1 = xs[5], dth = xs[6];
        double A[3][4];
#pragma unroll
        for (int i = 0; i < 3; ++i) {
            const double J0 = part[4 + i*7 + 0];
            const double J1 = part[4 + i*7 + 1];
            const double J2 = -x2*(double)part[4 + i*7 + 2] + x1*(double)part[4 + i*7 + 3];
            const double dL = (i == 0) ? (double)part[0]
                            : (i == 1) ? (double)part[1]
                            : (-x2*(double)part[2] + x1*(double)part[3]);
            A[i][0] = (double)part[4 + i*7 + 4] + (i == 0 ? EPS_REG : 0.0);
            A[i][1] = (double)part[4 + i*7 + 5] + (i == 1 ? EPS_REG : 0.0);
            A[i][2] = (double)part[4 + i*7 + 6] + (i == 2 ? EPS_REG : 0.0);
            A[i][3] = dL - (J0*dq0 + J1*dq1 + J2*dth);
        }
        for (int cc = 0; cc < 2; ++cc) {
            int piv = cc;
            double mx = fabs(A[cc][cc]);
            for (int rr = cc + 1; rr < 3; ++rr) {
                const double v = fabs(A[rr][cc]);
                if (v > mx) { mx = v; piv = rr; }
            }
            if (piv != cc) {
                for (int k2 = 0; k2 < 4; ++k2) {
                    const double tmp = A[cc][k2]; A[cc][k2] = A[piv][k2]; A[piv][k2] = tmp;
                }
            }
            const double inv = 1.0 / A[cc][cc];
            for (int rr = cc + 1; rr < 3; ++rr) {
                const double f = A[rr][cc] * inv;
                for (int k2 = cc + 1; k2 < 4; ++k2) A[rr][k2] -= f * A[cc][k2];
            }
        }
        const double sol2 = A[2][3] / A[2][2];
        const double sol1 = (A[1][3] - A[1][2]*sol2) / A[1][1];
        const double sol0 = (A[0][3] - A[0][1]*sol1 - A[0][2]*sol2) / A[0][0];
        float* o = out + (size_t)(samp0 + s)*7;
        o[0] = (float)dq0;
        o[1] = (float)dq1;
        o[2] = (float)(-x2*dth);
        o[3] = (float)( x1*dth);
        o[4] = (float)sol0;
        o[5] = (float)sol1;
        o[6] = (float)sol2;
    }
}

extern "C" void kernel_launch(void* const* d_in, const int* in_sizes, int n_in,
                              void* d_out, int out_size, void* d_ws, size_t ws_size,
                              hipStream_t stream) {
    const float* x  = (const float*)d_in[0];
    const float* W0 = (const float*)d_in[1];
    const float* b0 = (const float*)d_in[2];
    const float* W1 = (const float*)d_in[3];
    const float* b1 = (const float*)d_in[4];
    const float* W2 = (const float*)d_in[5];
    float* out = (float*)d_out;

    const int B = in_sizes[0] / 7;
    const size_t NEED = 6u * 65536u * sizeof(short);   // 768 KB of W1 fragments

    if (ws_size >= NEED && (B % 8) == 0) {
        short* ws = (short*)d_ws;
        prep_w1_frags<<<128, 128, 0, stream>>>(W1, ws);
        lnn_mfma32<<<B / 8, 512, 0, stream>>>(x, W0, b0, b1, W2, ws, out);
    } else {
        const int useT = (ws_size >= (size_t)HID * HID * sizeof(float)) ? 1 : 0;
        float* W1T = (float*)d_ws;
        if (useT) transpose_w1<<<64, 256, 0, stream>>>(W1, W1T);
        lnn_fused<<<B / TS8, 256, 0, stream>>>(x, W0, b0, W1, b1, W2, W1T, useT, out);
    }
}